// Round 2
// baseline (870.046 us; speedup 1.0000x reference)
//
#include <hip/hip_runtime.h>
#include <math.h>

#define B_ 2
#define T_ 2
#define H_ 28
#define W_ 28
#define S_ (H_*W_)      /* 784  */
#define L_ (T_*S_)      /* 1568 */
#define C_ 768
#define NH_ 12
#define HD_ 64
#define LN_EPS 1e-5f
#define SCALE 0.125f    /* hd^-0.5 */

// ---------------------------------------------------------------------------
// QKV GEMM: Y[m,n] = sum_k X[m,k] * Wq[n,k]; scatter into q/k/v [B,NH,L,HD]
// M=3136, N=2304, K=768. 64x64 tile, BK=16, 256 thr, 4x4 microtile.
// ---------------------------------------------------------------------------
__global__ __launch_bounds__(256) void qkv_gemm(
    const float* __restrict__ X, const float* __restrict__ Wq,
    float* __restrict__ q_raw, float* __restrict__ k_raw, float* __restrict__ v_raw) {
  __shared__ float As[16][68];
  __shared__ float Bs[16][68];
  const int tid = threadIdx.x;
  const int tx = tid & 15, ty = tid >> 4;
  const int m0 = blockIdx.y * 64;
  const int n0 = blockIdx.x * 64;
  const int lr = tid >> 2;          // 0..63 tile row
  const int lk = (tid & 3) * 4;     // 0,4,8,12
  float acc[4][4] = {};
  const float* aptr = X + (size_t)(m0 + lr) * C_ + lk;
  const float* bptr = Wq + (size_t)(n0 + lr) * C_ + lk;
  for (int k0 = 0; k0 < C_; k0 += 16) {
    float4 av = *(const float4*)(aptr + k0);
    float4 bv = *(const float4*)(bptr + k0);
    __syncthreads();
    As[lk+0][lr] = av.x; As[lk+1][lr] = av.y; As[lk+2][lr] = av.z; As[lk+3][lr] = av.w;
    Bs[lk+0][lr] = bv.x; Bs[lk+1][lr] = bv.y; Bs[lk+2][lr] = bv.z; Bs[lk+3][lr] = bv.w;
    __syncthreads();
    #pragma unroll
    for (int kk = 0; kk < 16; ++kk) {
      float4 a = *(const float4*)&As[kk][tx*4];
      float4 b = *(const float4*)&Bs[kk][ty*4];
      acc[0][0] += a.x*b.x; acc[0][1] += a.x*b.y; acc[0][2] += a.x*b.z; acc[0][3] += a.x*b.w;
      acc[1][0] += a.y*b.x; acc[1][1] += a.y*b.y; acc[1][2] += a.y*b.z; acc[1][3] += a.y*b.w;
      acc[2][0] += a.z*b.x; acc[2][1] += a.z*b.y; acc[2][2] += a.z*b.z; acc[2][3] += a.z*b.w;
      acc[3][0] += a.w*b.x; acc[3][1] += a.w*b.y; acc[3][2] += a.w*b.z; acc[3][3] += a.w*b.w;
    }
  }
  // n-tile (64 wide) lies entirely inside one (which, head) block
  const int which = n0 / C_;
  const int h = (n0 % C_) / HD_;
  float* dst = (which == 0) ? q_raw : ((which == 1) ? k_raw : v_raw);
  #pragma unroll
  for (int i = 0; i < 4; ++i) {
    const int gm = m0 + tx*4 + i;
    const int b = gm / L_, l = gm % L_;
    float4 o = make_float4(acc[i][0], acc[i][1], acc[i][2], acc[i][3]);
    *(float4*)&dst[(((size_t)b*NH_ + h)*L_ + l)*HD_ + ty*4] = o;
  }
}

// ---------------------------------------------------------------------------
// Depthwise 3x3 conv (pad 1) over (H,W) per frame + LayerNorm over HD.
// One wave per output row; lane = channel d. in/out: [B,NH,L,HD]
// ---------------------------------------------------------------------------
__global__ __launch_bounds__(256) void pool_ln(
    const float* __restrict__ in, const float* __restrict__ w,
    const float* __restrict__ g, const float* __restrict__ bta,
    float* __restrict__ out) {
  const int row = blockIdx.x * 4 + (threadIdx.x >> 6);  // 0..B*NH*L-1
  const int d = threadIdx.x & 63;
  const int bh = row / L_;
  const int l  = row % L_;
  const int t  = l / S_;
  const int sq = l % S_;
  const int x = sq / W_, y = sq % W_;
  const float* base = in + ((size_t)bh * L_ + t * S_) * HD_;
  float acc = 0.f;
  #pragma unroll
  for (int dx = 0; dx < 3; ++dx) {
    const int xx = x + dx - 1;
    if (xx < 0 || xx >= H_) continue;
    #pragma unroll
    for (int dy = 0; dy < 3; ++dy) {
      const int yy = y + dy - 1;
      if (yy < 0 || yy >= W_) continue;
      acc += base[(size_t)(xx * W_ + yy) * HD_ + d] * w[(dx * 3 + dy) * HD_ + d];
    }
  }
  // LayerNorm across the 64 lanes of this wave
  float s = acc;
  #pragma unroll
  for (int off = 32; off; off >>= 1) s += __shfl_xor(s, off);
  const float mu = s * (1.f / 64.f);
  const float dv = acc - mu;
  float s2 = dv * dv;
  #pragma unroll
  for (int off = 32; off; off >>= 1) s2 += __shfl_xor(s2, off);
  const float var = s2 * (1.f / 64.f);
  out[(size_t)row * HD_ + d] = dv * rsqrtf(var + LN_EPS) * g[d] + bta[d];
}

// ---------------------------------------------------------------------------
// rel_h[bh,t,sq,k] = dot(q_p[bh, t*S+sq, :], rel_pos_h[x-k+H-1, :])  (x=sq/W)
// rel_w[bh,t,sq,k] = dot(q_p[bh, t*S+sq, :], rel_pos_w[y-k+W-1, :])  (y=sq%W)
// ---------------------------------------------------------------------------
__global__ void relpos_kernel(
    const float* __restrict__ qp, const float* __restrict__ rph,
    const float* __restrict__ rpw, float* __restrict__ rel_h,
    float* __restrict__ rel_w) {
  const int idx = blockIdx.x * blockDim.x + threadIdx.x;  // grid sized exactly
  const int k = idx % H_;
  const int rest = idx / H_;           // (bh*T + t)*S + sq
  const int sq = rest % S_;
  const int x = sq / W_, y = sq % W_;
  const float* qrow = qp + (size_t)rest * HD_;   // (bh*T+t)*S+sq == bh*L + t*S + sq
  const float* rh = rph + (x - k + H_ - 1) * HD_;
  const float* rw = rpw + (y - k + W_ - 1) * HD_;
  float ah = 0.f, aw = 0.f;
  #pragma unroll 8
  for (int c = 0; c < HD_; ++c) {
    const float qv = qrow[c];
    ah += qv * rh[c];
    aw += qv * rw[c];
  }
  rel_h[idx] = ah;
  rel_w[idx] = aw;
}

// ---------------------------------------------------------------------------
// Flash-style attention per (bh, 32-row q tile). 256 threads.
// scores(32x32) -> bias on temporal-diagonal -> online softmax -> PV + resid.
// ---------------------------------------------------------------------------
__global__ __launch_bounds__(256) void attn_kernel(
    const float* __restrict__ qp, const float* __restrict__ kp,
    const float* __restrict__ vp, const float* __restrict__ relh,
    const float* __restrict__ relw, float* __restrict__ outp) {
  __shared__ float qs[32][68];
  __shared__ float ks[32][68];
  __shared__ float vs[32][68];
  __shared__ float st[32][33];
  __shared__ float mrow[32], lrow[32], frow[32];

  const int tid = threadIdx.x;
  const int qt = blockIdx.x;       // 0..48
  const int bh = blockIdx.y;       // 0..23
  const size_t base = (size_t)bh * L_ * HD_;

  const int sr = tid >> 3;         // staging/output row 0..31
  const int sc = (tid & 7) * 8;    // staging/output col base
  {
    const float* src = qp + base + (size_t)(qt * 32 + sr) * HD_ + sc;
    *(float4*)&qs[sr][sc]     = *(const float4*)src;
    *(float4*)&qs[sr][sc + 4] = *(const float4*)(src + 4);
  }
  if (tid < 32) { mrow[tid] = -INFINITY; lrow[tid] = 0.f; }

  float acc[8] = {0.f,0.f,0.f,0.f,0.f,0.f,0.f,0.f};
  const int ri = (tid & 15) * 2;   // score rows ri, ri+1
  const int cj = (tid >> 4) * 2;   // score cols cj, cj+1

  for (int kt = 0; kt < 49; ++kt) {
    __syncthreads();
    {
      const float* ksrc = kp + base + (size_t)(kt * 32 + sr) * HD_ + sc;
      const float* vsrc = vp + base + (size_t)(kt * 32 + sr) * HD_ + sc;
      *(float4*)&ks[sr][sc]     = *(const float4*)ksrc;
      *(float4*)&ks[sr][sc + 4] = *(const float4*)(ksrc + 4);
      *(float4*)&vs[sr][sc]     = *(const float4*)vsrc;
      *(float4*)&vs[sr][sc + 4] = *(const float4*)(vsrc + 4);
    }
    __syncthreads();
    // ---- scores: 2x2 per thread ----
    float s00 = 0.f, s01 = 0.f, s10 = 0.f, s11 = 0.f;
    #pragma unroll
    for (int d = 0; d < HD_; d += 4) {
      float4 k0v = *(const float4*)&ks[cj][d];
      float4 k1v = *(const float4*)&ks[cj + 1][d];
      float4 q0v = *(const float4*)&qs[ri][d];
      float4 q1v = *(const float4*)&qs[ri + 1][d];
      s00 += q0v.x*k0v.x + q0v.y*k0v.y + q0v.z*k0v.z + q0v.w*k0v.w;
      s01 += q0v.x*k1v.x + q0v.y*k1v.y + q0v.z*k1v.z + q0v.w*k1v.w;
      s10 += q1v.x*k0v.x + q1v.y*k0v.y + q1v.z*k0v.z + q1v.w*k0v.w;
      s11 += q1v.x*k1v.x + q1v.y*k1v.y + q1v.z*k1v.z + q1v.w*k1v.w;
    }
    st[ri][cj] = s00 * SCALE;     st[ri][cj + 1] = s01 * SCALE;
    st[ri + 1][cj] = s10 * SCALE; st[ri + 1][cj + 1] = s11 * SCALE;
    __syncthreads();
    // ---- bias + online softmax bookkeeping (one thread per q row) ----
    if (tid < 32) {
      const int r = tid;
      const int lq = qt * 32 + r;
      const int tq = lq / S_;
      const int sqq = lq % S_;
      const float* rh = relh + ((size_t)(bh * T_ + tq) * S_ + sqq) * H_;
      const float* rw = relw + ((size_t)(bh * T_ + tq) * S_ + sqq) * W_;
      const float m_old = mrow[r];
      float mx = m_old;
      const int lk0 = kt * 32;
      #pragma unroll
      for (int j = 0; j < 32; ++j) {
        const int lk = lk0 + j;
        float sv = st[r][j];
        if (lk / S_ == tq) {
          const int sk = lk % S_;
          sv += rh[sk / W_] + rw[sk % W_];
          st[r][j] = sv;
        }
        mx = fmaxf(mx, sv);
      }
      const float f = __expf(m_old - mx);
      float sum = 0.f;
      #pragma unroll
      for (int j = 0; j < 32; ++j) {
        const float p = __expf(st[r][j] - mx);
        st[r][j] = p;
        sum += p;
      }
      mrow[r] = mx;
      lrow[r] = lrow[r] * f + sum;
      frow[r] = f;
    }
    __syncthreads();
    // ---- PV accumulate: thread owns row sr, cols sc..sc+7 ----
    {
      const float f = frow[sr];
      #pragma unroll
      for (int c = 0; c < 8; ++c) acc[c] *= f;
      #pragma unroll 8
      for (int j = 0; j < 32; ++j) {
        const float p = st[sr][j];
        float4 v0 = *(const float4*)&vs[j][sc];
        float4 v1 = *(const float4*)&vs[j][sc + 4];
        acc[0] += p*v0.x; acc[1] += p*v0.y; acc[2] += p*v0.z; acc[3] += p*v0.w;
        acc[4] += p*v1.x; acc[5] += p*v1.y; acc[6] += p*v1.z; acc[7] += p*v1.w;
      }
    }
  }
  const float linv = 1.f / lrow[sr];
  float* dst = outp + base + (size_t)(qt * 32 + sr) * HD_ + sc;
  #pragma unroll
  for (int c = 0; c < 8; ++c) dst[c] = acc[c] * linv + qs[sr][sc + c];
}

// ---------------------------------------------------------------------------
// Output projection: out[b,l,n] = sum_c A[b, c/64, l, c%64] * Wo[n,c] + bo[n]
// M=3136, N=768, K=768.
// ---------------------------------------------------------------------------
__global__ __launch_bounds__(256) void proj_gemm(
    const float* __restrict__ A, const float* __restrict__ Wo,
    const float* __restrict__ bo, float* __restrict__ out) {
  __shared__ float As[16][68];
  __shared__ float Bs[16][68];
  const int tid = threadIdx.x;
  const int tx = tid & 15, ty = tid >> 4;
  const int m0 = blockIdx.y * 64;
  const int n0 = blockIdx.x * 64;
  const int lr = tid >> 2;
  const int lk = (tid & 3) * 4;
  float acc[4][4] = {};
  const int gm = m0 + lr;
  const int b = gm / L_, l = gm % L_;
  const float* bptr = Wo + (size_t)(n0 + lr) * C_ + lk;
  for (int k0 = 0; k0 < C_; k0 += 16) {
    const int k = k0 + lk;
    const int h = k >> 6, d = k & 63;
    float4 av = *(const float4*)&A[(((size_t)b * NH_ + h) * L_ + l) * HD_ + d];
    float4 bv = *(const float4*)(bptr + k0);
    __syncthreads();
    As[lk+0][lr] = av.x; As[lk+1][lr] = av.y; As[lk+2][lr] = av.z; As[lk+3][lr] = av.w;
    Bs[lk+0][lr] = bv.x; Bs[lk+1][lr] = bv.y; Bs[lk+2][lr] = bv.z; Bs[lk+3][lr] = bv.w;
    __syncthreads();
    #pragma unroll
    for (int kk = 0; kk < 16; ++kk) {
      float4 a = *(const float4*)&As[kk][tx*4];
      float4 bb = *(const float4*)&Bs[kk][ty*4];
      acc[0][0] += a.x*bb.x; acc[0][1] += a.x*bb.y; acc[0][2] += a.x*bb.z; acc[0][3] += a.x*bb.w;
      acc[1][0] += a.y*bb.x; acc[1][1] += a.y*bb.y; acc[1][2] += a.y*bb.z; acc[1][3] += a.y*bb.w;
      acc[2][0] += a.z*bb.x; acc[2][1] += a.z*bb.y; acc[2][2] += a.z*bb.z; acc[2][3] += a.z*bb.w;
      acc[3][0] += a.w*bb.x; acc[3][1] += a.w*bb.y; acc[3][2] += a.w*bb.z; acc[3][3] += a.w*bb.w;
    }
  }
  #pragma unroll
  for (int i = 0; i < 4; ++i) {
    const int gm2 = m0 + tx*4 + i;
    const int n = n0 + ty*4;
    float4 o;
    o.x = acc[i][0] + bo[n + 0];
    o.y = acc[i][1] + bo[n + 1];
    o.z = acc[i][2] + bo[n + 2];
    o.w = acc[i][3] + bo[n + 3];
    *(float4*)&out[(size_t)gm2 * C_ + n] = o;
  }
}

// ---------------------------------------------------------------------------
extern "C" void kernel_launch(void* const* d_in, const int* in_sizes, int n_in,
                              void* d_out, int out_size, void* d_ws, size_t ws_size,
                              hipStream_t stream) {
  const float* x         = (const float*)d_in[0];
  const float* qkv_w     = (const float*)d_in[1];
  const float* out_w     = (const float*)d_in[2];
  const float* out_b     = (const float*)d_in[3];
  const float* q_pool_w  = (const float*)d_in[4];
  const float* k_pool_w  = (const float*)d_in[5];
  const float* v_pool_w  = (const float*)d_in[6];
  const float* q_ln_g    = (const float*)d_in[7];
  const float* q_ln_b    = (const float*)d_in[8];
  const float* k_ln_g    = (const float*)d_in[9];
  const float* k_ln_b    = (const float*)d_in[10];
  const float* v_ln_g    = (const float*)d_in[11];
  const float* v_ln_b    = (const float*)d_in[12];
  const float* rel_pos_h = (const float*)d_in[13];
  const float* rel_pos_w = (const float*)d_in[14];

  float* ws = (float*)d_ws;
  const size_t NQ = (size_t)B_ * NH_ * L_ * HD_;   // 2,408,448
  float* q_raw = ws + 0 * NQ;
  float* k_raw = ws + 1 * NQ;
  float* v_raw = ws + 2 * NQ;
  float* q_p   = ws + 3 * NQ;
  float* k_p   = ws + 4 * NQ;
  float* v_p   = ws + 5 * NQ;
  float* attn_o = q_raw;   // q_raw dead after q pooling
  float* rel_h  = k_raw;   // k_raw dead after k pooling (needs 1,053,696 floats)
  float* rel_w  = v_raw;   // v_raw dead after v pooling

  qkv_gemm<<<dim3(36, 49), 256, 0, stream>>>(x, qkv_w, q_raw, k_raw, v_raw);
  pool_ln<<<9408, 256, 0, stream>>>(q_raw, q_pool_w, q_ln_g, q_ln_b, q_p);
  pool_ln<<<9408, 256, 0, stream>>>(k_raw, k_pool_w, k_ln_g, k_ln_b, k_p);
  pool_ln<<<9408, 256, 0, stream>>>(v_raw, v_pool_w, v_ln_g, v_ln_b, v_p);
  relpos_kernel<<<4116, 256, 0, stream>>>(q_p, rel_pos_h, rel_pos_w, rel_h, rel_w);
  attn_kernel<<<dim3(49, 24), 256, 0, stream>>>(q_p, k_p, v_p, rel_h, rel_w, attn_o);
  proj_gemm<<<dim3(12, 49), 256, 0, stream>>>(attn_o, out_w, out_b, (float*)d_out);
}

// Round 3
// 409.684 us; speedup vs baseline: 2.1237x; 2.1237x over previous
//
#include <hip/hip_runtime.h>
#include <math.h>

#define B_ 2
#define T_ 2
#define H_ 28
#define W_ 28
#define S_ (H_*W_)      /* 784  */
#define L_ (T_*S_)      /* 1568 */
#define C_ 768
#define NH_ 12
#define HD_ 64
#define LN_EPS 1e-5f
#define LOG2E 1.4426950408889634f
#define SCALE_K (0.125f * LOG2E)   /* hd^-0.5 * log2e folded into K' */
#define DP_ 176                     /* augmented head dim: 64 + 2*2*28 */

typedef unsigned int uint_;
typedef unsigned int u32x4 __attribute__((ext_vector_type(4)));
typedef __bf16 bf16x8 __attribute__((ext_vector_type(8)));
typedef float f32x16 __attribute__((ext_vector_type(16)));

#define BC8(x) __builtin_bit_cast(bf16x8, (x))

__device__ __forceinline__ unsigned short f2bf(float f) {
  uint_ u = __builtin_bit_cast(uint_, f);
  u += 0x7FFFu + ((u >> 16) & 1u);
  return (unsigned short)(u >> 16);
}

__device__ __forceinline__ uint_ cvtpk(float a, float b) {
  uint_ r;
  asm("v_cvt_pk_bf16_f32 %0, %1, %2" : "=v"(r) : "v"(a), "v"(b));
  return r;
}

// ---------------------------------------------------------------------------
// QKV GEMM (f32): Y[m,n] = sum_k X[m,k]*Wq[n,k]; scatter into q/k/v [B,NH,L,HD]
// ---------------------------------------------------------------------------
__global__ __launch_bounds__(256) void qkv_gemm(
    const float* __restrict__ X, const float* __restrict__ Wq,
    float* __restrict__ q_raw, float* __restrict__ k_raw, float* __restrict__ v_raw) {
  __shared__ float As[16][68];
  __shared__ float Bs[16][68];
  const int tid = threadIdx.x;
  const int tx = tid & 15, ty = tid >> 4;
  const int m0 = blockIdx.y * 64;
  const int n0 = blockIdx.x * 64;
  const int lr = tid >> 2;
  const int lk = (tid & 3) * 4;
  float acc[4][4] = {};
  const float* aptr = X + (size_t)(m0 + lr) * C_ + lk;
  const float* bptr = Wq + (size_t)(n0 + lr) * C_ + lk;
  for (int k0 = 0; k0 < C_; k0 += 16) {
    float4 av = *(const float4*)(aptr + k0);
    float4 bv = *(const float4*)(bptr + k0);
    __syncthreads();
    As[lk+0][lr] = av.x; As[lk+1][lr] = av.y; As[lk+2][lr] = av.z; As[lk+3][lr] = av.w;
    Bs[lk+0][lr] = bv.x; Bs[lk+1][lr] = bv.y; Bs[lk+2][lr] = bv.z; Bs[lk+3][lr] = bv.w;
    __syncthreads();
    #pragma unroll
    for (int kk = 0; kk < 16; ++kk) {
      float4 a = *(const float4*)&As[kk][tx*4];
      float4 b = *(const float4*)&Bs[kk][ty*4];
      acc[0][0] += a.x*b.x; acc[0][1] += a.x*b.y; acc[0][2] += a.x*b.z; acc[0][3] += a.x*b.w;
      acc[1][0] += a.y*b.x; acc[1][1] += a.y*b.y; acc[1][2] += a.y*b.z; acc[1][3] += a.y*b.w;
      acc[2][0] += a.z*b.x; acc[2][1] += a.z*b.y; acc[2][2] += a.z*b.z; acc[2][3] += a.z*b.w;
      acc[3][0] += a.w*b.x; acc[3][1] += a.w*b.y; acc[3][2] += a.w*b.z; acc[3][3] += a.w*b.w;
    }
  }
  const int which = n0 / C_;
  const int h = (n0 % C_) / HD_;
  float* dst = (which == 0) ? q_raw : ((which == 1) ? k_raw : v_raw);
  #pragma unroll
  for (int i = 0; i < 4; ++i) {
    const int gm = m0 + tx*4 + i;
    const int b = gm / L_, l = gm % L_;
    float4 o = make_float4(acc[i][0], acc[i][1], acc[i][2], acc[i][3]);
    *(float4*)&dst[(((size_t)b*NH_ + h)*L_ + l)*HD_ + ty*4] = o;
  }
}

// ---------------------------------------------------------------------------
// Depthwise 3x3 conv + LayerNorm(64). Optional f32 out and bf16 out (scaled).
// ---------------------------------------------------------------------------
__global__ __launch_bounds__(256) void pool_ln_multi(
    const float* __restrict__ in, const float* __restrict__ w,
    const float* __restrict__ g, const float* __restrict__ bta,
    float* __restrict__ f32out, unsigned short* __restrict__ bf16out,
    int bfstride, float scale) {
  const int row = blockIdx.x * 4 + (threadIdx.x >> 6);
  const int d = threadIdx.x & 63;
  const int bh = row / L_;
  const int l  = row % L_;
  const int t  = l / S_;
  const int sq = l % S_;
  const int x = sq / W_, y = sq % W_;
  const float* base = in + ((size_t)bh * L_ + t * S_) * HD_;
  float acc = 0.f;
  #pragma unroll
  for (int dx = 0; dx < 3; ++dx) {
    const int xx = x + dx - 1;
    if (xx < 0 || xx >= H_) continue;
    #pragma unroll
    for (int dy = 0; dy < 3; ++dy) {
      const int yy = y + dy - 1;
      if (yy < 0 || yy >= W_) continue;
      acc += base[(size_t)(xx * W_ + yy) * HD_ + d] * w[(dx * 3 + dy) * HD_ + d];
    }
  }
  float s = acc;
  #pragma unroll
  for (int off = 32; off; off >>= 1) s += __shfl_xor(s, off);
  const float mu = s * (1.f / 64.f);
  const float dv = acc - mu;
  float s2 = dv * dv;
  #pragma unroll
  for (int off = 32; off; off >>= 1) s2 += __shfl_xor(s2, off);
  const float var = s2 * (1.f / 64.f);
  const float val = dv * rsqrtf(var + LN_EPS) * g[d] + bta[d];
  if (f32out) f32out[(size_t)row * HD_ + d] = val;
  bf16out[(size_t)row * bfstride + d] = f2bf(val * scale);
}

// ---------------------------------------------------------------------------
// Transpose V per head: Vtmp [bh][L][64] bf16 -> VpT [bh][64][L] bf16
// ---------------------------------------------------------------------------
__global__ __launch_bounds__(256) void transpose_v(
    const unsigned short* __restrict__ Vtmp, unsigned short* __restrict__ VpT) {
  __shared__ unsigned short tile[32][72];
  const int bh = blockIdx.y;
  const int l0 = blockIdx.x * 32;
  const int t = threadIdx.x;
  {
    const int r = t >> 3, c8 = (t & 7) * 8;
    u32x4 v = *(const u32x4*)(Vtmp + ((size_t)bh * L_ + l0 + r) * 64 + c8);
    *(u32x4*)&tile[r][c8] = v;
  }
  __syncthreads();
  const int d = t >> 2, gq = t & 3;
  unsigned short o[8];
  #pragma unroll
  for (int i = 0; i < 8; ++i) o[i] = tile[gq*8 + i][d];
  u32x4 ov;
  ov.x = (uint_)o[0] | ((uint_)o[1] << 16);
  ov.y = (uint_)o[2] | ((uint_)o[3] << 16);
  ov.z = (uint_)o[4] | ((uint_)o[5] << 16);
  ov.w = (uint_)o[6] | ((uint_)o[7] << 16);
  *(u32x4*)(VpT + ((size_t)bh * 64 + d) * L_ + l0 + gq*8) = ov;
}

// ---------------------------------------------------------------------------
// rel-pos rows -> Qp2 dims 64..175 (log2e-scaled bf16; other T-block zeroed)
// ---------------------------------------------------------------------------
__global__ void relpos_fused(
    const float* __restrict__ qp, const float* __restrict__ rph,
    const float* __restrict__ rpw, unsigned short* __restrict__ Qp2) {
  const int idx = blockIdx.x * blockDim.x + threadIdx.x;
  const int k = idx % H_;
  const int rest = idx / H_;            // bh*L + t*S + sq
  const int sq = rest % S_;
  const int t = (rest % L_) / S_;
  const int x = sq / W_, y = sq % W_;
  const float* qrow = qp + (size_t)rest * HD_;
  const float* rh = rph + (x - k + H_ - 1) * HD_;
  const float* rw = rpw + (y - k + W_ - 1) * HD_;
  float ah = 0.f, aw = 0.f;
  #pragma unroll 8
  for (int c = 0; c < HD_; ++c) {
    const float qv = qrow[c];
    ah += qv * rh[c];
    aw += qv * rw[c];
  }
  unsigned short* qd = Qp2 + (size_t)rest * DP_;
  qd[64 + t*56 + k]        = f2bf(ah * LOG2E);
  qd[64 + t*56 + 28 + k]   = f2bf(aw * LOG2E);
  qd[64 + (1-t)*56 + k]      = 0;
  qd[64 + (1-t)*56 + 28 + k] = 0;
}

// ---------------------------------------------------------------------------
// MFMA flash attention. Block = 128 thr (2 waves), grid (49, 24).
// Wave splits KV (25/24 tiles of 32); merge via LDS at end.
// ---------------------------------------------------------------------------
__device__ __forceinline__ void load_tile(
    const unsigned short* kbase, const unsigned short* vbase0, int kt,
    u32x4& k0, u32x4& k1, u32x4& k2, u32x4& k3,
    u32x4& va, u32x4& vb, u32x4& vc, u32x4& vd) {
  const unsigned short* kr = kbase + (size_t)kt * 2048;
  k0 = *(const u32x4*)(kr);
  k1 = *(const u32x4*)(kr + 16);
  k2 = *(const u32x4*)(kr + 32);
  k3 = *(const u32x4*)(kr + 48);
  const unsigned short* vr = vbase0 + kt * 32;
  va = *(const u32x4*)(vr);
  vb = *(const u32x4*)(vr + 16);
  vc = *(const u32x4*)(vr + 32 * L_);
  vd = *(const u32x4*)(vr + 32 * L_ + 16);
}

__device__ __forceinline__ void proc_tile(
    int kt, int lo, int hi, const u32x4 (&qf)[11],
    u32x4 k0, u32x4 k1, u32x4 k2, u32x4 k3,
    u32x4 va, u32x4 vb, u32x4 vc, u32x4 vd,
    f32x16& acc0, f32x16& acc1, float& m_run, float& l_run) {
  // one-hot params for this lane's K' row
  const int kr = kt * 32 + lo;
  const int t = (kr >= S_) ? 1 : 0;
  const int sk = kr - t * S_;
  const int x = sk / W_, y = sk - x * W_;
  const int p1 = 64 + t*56 + x;
  const int p2 = 64 + t*56 + 28 + y;
  const uint_ v1 = 0x3F80u << ((p1 & 1) << 4);
  const uint_ v2 = 0x3F80u << ((p2 & 1) << 4);
  const int g1 = p1 >> 3, g2 = p2 >> 3;
  const int w1 = (p1 >> 1) & 3, w2 = (p2 >> 1) & 3;

  f32x16 s = {};
  s = __builtin_amdgcn_mfma_f32_32x32x16_bf16(BC8(k0), BC8(qf[0]), s, 0, 0, 0);
  s = __builtin_amdgcn_mfma_f32_32x32x16_bf16(BC8(k1), BC8(qf[1]), s, 0, 0, 0);
  s = __builtin_amdgcn_mfma_f32_32x32x16_bf16(BC8(k2), BC8(qf[2]), s, 0, 0, 0);
  s = __builtin_amdgcn_mfma_f32_32x32x16_bf16(BC8(k3), BC8(qf[3]), s, 0, 0, 0);
  #pragma unroll
  for (int c = 4; c < 11; ++c) {
    const int gg = 2*c + hi;
    u32x4 oh;
    oh.x = ((g1 == gg && w1 == 0) ? v1 : 0u) | ((g2 == gg && w2 == 0) ? v2 : 0u);
    oh.y = ((g1 == gg && w1 == 1) ? v1 : 0u) | ((g2 == gg && w2 == 1) ? v2 : 0u);
    oh.z = ((g1 == gg && w1 == 2) ? v1 : 0u) | ((g2 == gg && w2 == 2) ? v2 : 0u);
    oh.w = ((g1 == gg && w1 == 3) ? v1 : 0u) | ((g2 == gg && w2 == 3) ? v2 : 0u);
    s = __builtin_amdgcn_mfma_f32_32x32x16_bf16(BC8(oh), BC8(qf[c]), s, 0, 0, 0);
  }

  // online softmax (q = lo lane-local; lanes lo and lo+32 hold same q state)
  float pmax = s[0];
  #pragma unroll
  for (int r = 1; r < 16; ++r) pmax = fmaxf(pmax, s[r]);
  pmax = fmaxf(pmax, __shfl_xor(pmax, 32));
  if (__any(pmax > m_run + 8.f)) {            // defer-max (log2 units)
    const float mn = fmaxf(m_run, pmax);
    const float f = exp2f(m_run - mn);
    m_run = mn; l_run *= f;
    #pragma unroll
    for (int r = 0; r < 16; ++r) {
      const float fr = __shfl(f, (r & 3) + 8*(r >> 2) + 4*hi);
      acc0[r] *= fr; acc1[r] *= fr;
    }
  }
  float ps = 0.f;
  uint_ pw0, pw1, pw2, pw3, pw4, pw5, pw6, pw7;
  {
    float a, b;
    a = exp2f(s[0]-m_run);  b = exp2f(s[1]-m_run);  ps += a+b; pw0 = cvtpk(a,b);
    a = exp2f(s[2]-m_run);  b = exp2f(s[3]-m_run);  ps += a+b; pw1 = cvtpk(a,b);
    a = exp2f(s[4]-m_run);  b = exp2f(s[5]-m_run);  ps += a+b; pw2 = cvtpk(a,b);
    a = exp2f(s[6]-m_run);  b = exp2f(s[7]-m_run);  ps += a+b; pw3 = cvtpk(a,b);
    a = exp2f(s[8]-m_run);  b = exp2f(s[9]-m_run);  ps += a+b; pw4 = cvtpk(a,b);
    a = exp2f(s[10]-m_run); b = exp2f(s[11]-m_run); ps += a+b; pw5 = cvtpk(a,b);
    a = exp2f(s[12]-m_run); b = exp2f(s[13]-m_run); ps += a+b; pw6 = cvtpk(a,b);
    a = exp2f(s[14]-m_run); b = exp2f(s[15]-m_run); ps += a+b; pw7 = cvtpk(a,b);
  }
  ps += __shfl_xor(ps, 32);
  l_run += ps;

  // P^T -> PV A-fragments via permlane32_swap (T12)
  auto sA = __builtin_amdgcn_permlane32_swap(pw0, pw2, false, false);
  auto sB = __builtin_amdgcn_permlane32_swap(pw1, pw3, false, false);
  auto sC = __builtin_amdgcn_permlane32_swap(pw4, pw6, false, false);
  auto sD = __builtin_amdgcn_permlane32_swap(pw5, pw7, false, false);
  u32x4 pa0, pa1;
  pa0.x = sA[0]; pa0.y = sB[0]; pa0.z = sA[1]; pa0.w = sB[1];
  pa1.x = sC[0]; pa1.y = sD[0]; pa1.z = sC[1]; pa1.w = sD[1];

  acc0 = __builtin_amdgcn_mfma_f32_32x32x16_bf16(BC8(pa0), BC8(va), acc0, 0, 0, 0);
  acc0 = __builtin_amdgcn_mfma_f32_32x32x16_bf16(BC8(pa1), BC8(vb), acc0, 0, 0, 0);
  acc1 = __builtin_amdgcn_mfma_f32_32x32x16_bf16(BC8(pa0), BC8(vc), acc1, 0, 0, 0);
  acc1 = __builtin_amdgcn_mfma_f32_32x32x16_bf16(BC8(pa1), BC8(vd), acc1, 0, 0, 0);
}

__global__ __launch_bounds__(128) void attn_mfma(
    const unsigned short* __restrict__ Qp2, const unsigned short* __restrict__ Kp2a,
    const unsigned short* __restrict__ VpT, const float* __restrict__ qres,
    float* __restrict__ outp) {
  __shared__ float red_acc[32][64];
  __shared__ float red_ml[2][2][32];

  const int lane = threadIdx.x & 63;
  const int wv = threadIdx.x >> 6;      // 0,1
  const int lo = lane & 31, hi = lane >> 5;
  const int qt = blockIdx.x;            // 0..48
  const int bh = blockIdx.y;            // 0..23
  const int q0 = qt * 32;

  u32x4 qf[11];
  {
    const unsigned short* qrow = Qp2 + ((size_t)bh * L_ + q0 + lo) * DP_ + hi * 8;
    #pragma unroll
    for (int c = 0; c < 11; ++c) qf[c] = *(const u32x4*)(qrow + c * 16);
  }

  const unsigned short* kbase = Kp2a + ((size_t)bh * L_ + lo) * 64 + hi * 8;
  const unsigned short* vbase0 = VpT + (size_t)bh * 64 * L_ + (size_t)lo * L_ + hi * 8;

  f32x16 acc0 = {}, acc1 = {};
  float m_run = -1e30f, l_run = 0.f;
  const int nt = 25 - wv;
  const int tb = wv * 25;

  u32x4 ck0, ck1, ck2, ck3, cva, cvb, cvc, cvd;
  u32x4 nk0, nk1, nk2, nk3, nva, nvb, nvc, nvd;
  load_tile(kbase, vbase0, tb, ck0, ck1, ck2, ck3, cva, cvb, cvc, cvd);
  int i = 0;
  for (; i + 2 <= nt; i += 2) {
    load_tile(kbase, vbase0, tb + i + 1, nk0, nk1, nk2, nk3, nva, nvb, nvc, nvd);
    proc_tile(tb + i, lo, hi, qf, ck0, ck1, ck2, ck3, cva, cvb, cvc, cvd,
              acc0, acc1, m_run, l_run);
    const int nxt = tb + ((i + 2 < nt) ? i + 2 : nt - 1);
    load_tile(kbase, vbase0, nxt, ck0, ck1, ck2, ck3, cva, cvb, cvc, cvd);
    proc_tile(tb + i + 1, lo, hi, qf, nk0, nk1, nk2, nk3, nva, nvb, nvc, nvd,
              acc0, acc1, m_run, l_run);
  }
  if (i < nt)
    proc_tile(tb + i, lo, hi, qf, ck0, ck1, ck2, ck3, cva, cvb, cvc, cvd,
              acc0, acc1, m_run, l_run);

  // merge the two waves' partial states
  if (hi == 0) { red_ml[wv][0][lo] = m_run; red_ml[wv][1][lo] = l_run; }
  if (wv == 1) {
    #pragma unroll
    for (int r = 0; r < 16; ++r) {
      const int row = (r & 3) + 8*(r >> 2) + 4*hi;
      red_acc[row][lo]      = acc0[r];
      red_acc[row][32 + lo] = acc1[r];
    }
  }
  __syncthreads();
  if (wv == 0) {
    #pragma unroll
    for (int r = 0; r < 16; ++r) {
      const int row = (r & 3) + 8*(r >> 2) + 4*hi;
      const float m0 = red_ml[0][0][row], l0 = red_ml[0][1][row];
      const float m1 = red_ml[1][0][row], l1 = red_ml[1][1][row];
      const float M = fmaxf(m0, m1);
      const float w0 = exp2f(m0 - M), w1 = exp2f(m1 - M);
      const float inv = 1.0f / (l0 * w0 + l1 * w1);
      const float o0 = (acc0[r] * w0 + red_acc[row][lo] * w1) * inv;
      const float o1 = (acc1[r] * w0 + red_acc[row][32 + lo] * w1) * inv;
      const size_t off = ((size_t)bh * L_ + q0 + row) * HD_ + lo;
      outp[off]      = o0 + qres[off];
      outp[off + 32] = o1 + qres[off + 32];
    }
  }
}

// ---------------------------------------------------------------------------
// Output projection (f32): out[b,l,n] = sum_c A[b,c/64,l,c%64]*Wo[n,c] + bo[n]
// ---------------------------------------------------------------------------
__global__ __launch_bounds__(256) void proj_gemm(
    const float* __restrict__ A, const float* __restrict__ Wo,
    const float* __restrict__ bo, float* __restrict__ out) {
  __shared__ float As[16][68];
  __shared__ float Bs[16][68];
  const int tid = threadIdx.x;
  const int tx = tid & 15, ty = tid >> 4;
  const int m0 = blockIdx.y * 64;
  const int n0 = blockIdx.x * 64;
  const int lr = tid >> 2;
  const int lk = (tid & 3) * 4;
  float acc[4][4] = {};
  const int gm = m0 + lr;
  const int b = gm / L_, l = gm % L_;
  const float* bptr = Wo + (size_t)(n0 + lr) * C_ + lk;
  for (int k0 = 0; k0 < C_; k0 += 16) {
    const int k = k0 + lk;
    const int h = k >> 6, d = k & 63;
    float4 av = *(const float4*)&A[(((size_t)b * NH_ + h) * L_ + l) * HD_ + d];
    float4 bv = *(const float4*)(bptr + k0);
    __syncthreads();
    As[lk+0][lr] = av.x; As[lk+1][lr] = av.y; As[lk+2][lr] = av.z; As[lk+3][lr] = av.w;
    Bs[lk+0][lr] = bv.x; Bs[lk+1][lr] = bv.y; Bs[lk+2][lr] = bv.z; Bs[lk+3][lr] = bv.w;
    __syncthreads();
    #pragma unroll
    for (int kk = 0; kk < 16; ++kk) {
      float4 a = *(const float4*)&As[kk][tx*4];
      float4 bb = *(const float4*)&Bs[kk][ty*4];
      acc[0][0] += a.x*bb.x; acc[0][1] += a.x*bb.y; acc[0][2] += a.x*bb.z; acc[0][3] += a.x*bb.w;
      acc[1][0] += a.y*bb.x; acc[1][1] += a.y*bb.y; acc[1][2] += a.y*bb.z; acc[1][3] += a.y*bb.w;
      acc[2][0] += a.z*bb.x; acc[2][1] += a.z*bb.y; acc[2][2] += a.z*bb.z; acc[2][3] += a.z*bb.w;
      acc[3][0] += a.w*bb.x; acc[3][1] += a.w*bb.y; acc[3][2] += a.w*bb.z; acc[3][3] += a.w*bb.w;
    }
  }
  #pragma unroll
  for (int i = 0; i < 4; ++i) {
    const int gm2 = m0 + tx*4 + i;
    const int n = n0 + ty*4;
    float4 o;
    o.x = acc[i][0] + bo[n + 0];
    o.y = acc[i][1] + bo[n + 1];
    o.z = acc[i][2] + bo[n + 2];
    o.w = acc[i][3] + bo[n + 3];
    *(float4*)&out[(size_t)gm2 * C_ + n] = o;
  }
}

// ---------------------------------------------------------------------------
extern "C" void kernel_launch(void* const* d_in, const int* in_sizes, int n_in,
                              void* d_out, int out_size, void* d_ws, size_t ws_size,
                              hipStream_t stream) {
  const float* x         = (const float*)d_in[0];
  const float* qkv_w     = (const float*)d_in[1];
  const float* out_w     = (const float*)d_in[2];
  const float* out_b     = (const float*)d_in[3];
  const float* q_pool_w  = (const float*)d_in[4];
  const float* k_pool_w  = (const float*)d_in[5];
  const float* v_pool_w  = (const float*)d_in[6];
  const float* q_ln_g    = (const float*)d_in[7];
  const float* q_ln_b    = (const float*)d_in[8];
  const float* k_ln_g    = (const float*)d_in[9];
  const float* k_ln_b    = (const float*)d_in[10];
  const float* v_ln_g    = (const float*)d_in[11];
  const float* v_ln_b    = (const float*)d_in[12];
  const float* rel_pos_h = (const float*)d_in[13];
  const float* rel_pos_w = (const float*)d_in[14];

  float* R = (float*)d_ws;
  const size_t NQ = (size_t)B_ * NH_ * L_ * HD_;   // 2,408,448
  const size_t HB = NQ / 2;                        // 1,204,224 (bf16 half-size in f32 slots)
  float* q_raw = R;
  float* attn_o = R;                               // alias: q_raw dead after pool_q
  float* k_raw = R + NQ;
  unsigned short* Qp2 = (unsigned short*)(R + NQ); // spans into v_raw region (after pool_v)
  float* v_raw = R + 2*NQ;
  unsigned short* VpT = (unsigned short*)(R + 3*NQ - HB);
  float* q_p   = R + 3*NQ;
  unsigned short* Kp2a = (unsigned short*)(R + 4*NQ);
  unsigned short* Vtmp = (unsigned short*)(R + 4*NQ + HB);

  qkv_gemm<<<dim3(36, 49), 256, 0, stream>>>(x, qkv_w, q_raw, k_raw, v_raw);
  // order matters: k first (frees k_raw region head for Qp2), then v, then q
  pool_ln_multi<<<9408, 256, 0, stream>>>(k_raw, k_pool_w, k_ln_g, k_ln_b,
                                          nullptr, Kp2a, 64, SCALE_K);
  pool_ln_multi<<<9408, 256, 0, stream>>>(v_raw, v_pool_w, v_ln_g, v_ln_b,
                                          nullptr, Vtmp, 64, 1.f);
  pool_ln_multi<<<9408, 256, 0, stream>>>(q_raw, q_pool_w, q_ln_g, q_ln_b,
                                          q_p, Qp2, DP_, 1.f);
  transpose_v<<<dim3(49, 24), 256, 0, stream>>>(Vtmp, VpT);
  relpos_fused<<<4116, 256, 0, stream>>>(q_p, rel_pos_h, rel_pos_w, Qp2);
  attn_mfma<<<dim3(49, 24), 128, 0, stream>>>(Qp2, Kp2a, VpT, q_p, attn_o);
  proj_gemm<<<dim3(12, 49), 256, 0, stream>>>(attn_o, out_w, out_b, (float*)d_out);
}

// Round 4
// 258.841 us; speedup vs baseline: 3.3613x; 1.5828x over previous
//
#include <hip/hip_runtime.h>
#include <math.h>

#define B_ 2
#define T_ 2
#define H_ 28
#define W_ 28
#define S_ (H_*W_)      /* 784  */
#define L_ (T_*S_)      /* 1568 */
#define C_ 768
#define NH_ 12
#define HD_ 64
#define LN_EPS 1e-5f
#define LOG2E 1.4426950408889634f
#define SCALE_K (0.125f * LOG2E)   /* hd^-0.5 * log2e folded into K' */
#define DP_ 176                     /* augmented head dim: 64 + 2*2*28 */
#define MPAD 3200                   /* 3136 padded to 25*128 */

typedef unsigned int uint_;
typedef unsigned int u32x4 __attribute__((ext_vector_type(4)));
typedef __bf16 bf16x8 __attribute__((ext_vector_type(8)));
typedef float f32x4 __attribute__((ext_vector_type(4)));
typedef float f32x16 __attribute__((ext_vector_type(16)));

#define BC8(x) __builtin_bit_cast(bf16x8, (x))

__device__ __forceinline__ unsigned short f2bf(float f) {
  uint_ u = __builtin_bit_cast(uint_, f);
  u += 0x7FFFu + ((u >> 16) & 1u);
  return (unsigned short)(u >> 16);
}
__device__ __forceinline__ float bf2f(unsigned short h) {
  return __builtin_bit_cast(float, ((uint_)h) << 16);
}
__device__ __forceinline__ uint_ cvtpk(float a, float b) {
  uint_ r;
  asm("v_cvt_pk_bf16_f32 %0, %1, %2" : "=v"(r) : "v"(a), "v"(b));
  return r;
}
__device__ __forceinline__ void gload16(const void* g, void* l) {
  __builtin_amdgcn_global_load_lds(
      (const __attribute__((address_space(1))) unsigned int*)g,
      (__attribute__((address_space(3))) unsigned int*)l, 16, 0, 0);
}

// ---------------------------------------------------------------------------
// f32 -> bf16 convert, zero-pad tail (i in [n_src, n_total))
// ---------------------------------------------------------------------------
__global__ __launch_bounds__(256) void cvt_bf16(
    const float* __restrict__ src, unsigned short* __restrict__ dst,
    int n_src, int n_total) {
  const int i = (blockIdx.x * 256 + threadIdx.x) * 8;
  if (i >= n_total) return;
  u32x4 o;
  if (i < n_src) {
    float4 a = *(const float4*)(src + i);
    float4 b = *(const float4*)(src + i + 4);
    o.x = cvtpk(a.x, a.y); o.y = cvtpk(a.z, a.w);
    o.z = cvtpk(b.x, b.y); o.w = cvtpk(b.z, b.w);
  } else {
    o.x = 0; o.y = 0; o.z = 0; o.w = 0;
  }
  *(u32x4*)(dst + i) = o;
}

// ---------------------------------------------------------------------------
// bf16 MFMA GEMM core: C = A * B^T, 128x128 tile, BK=32, 4 waves (2x2 of 64x64)
// A: [>=m0+128][K] bf16 row-major, B: [>=n0+128][K] bf16 row-major.
// m97 structure: global_load_lds w16, linear LDS, 2 barriers/K-step.
// ---------------------------------------------------------------------------
__device__ __forceinline__ void gemm_core(
    const unsigned short* __restrict__ A, const unsigned short* __restrict__ Bm,
    int K, int m0, int n0, f32x4 (&acc)[4][4]) {
  __shared__ __align__(16) unsigned short As[128 * 32];
  __shared__ __align__(16) unsigned short Bs[128 * 32];
  const int tid = threadIdx.x;
  const int lane = tid & 63;
  const int wv = tid >> 6;
  const int wm = wv >> 1, wn = wv & 1;
  const int srow = tid >> 2, scol = (tid & 3) * 8;
  const int fr = lane & 15, fk = (lane >> 4) * 8;
  const unsigned short* ag = A + (size_t)(m0 + srow) * K + scol;
  const unsigned short* bg = Bm + (size_t)(n0 + srow) * K + scol;
  unsigned short* asd = As + tid * 8;
  unsigned short* bsd = Bs + tid * 8;
  const int arow = wm * 64 + fr;
  const int brow = wn * 64 + fr;
  for (int k0 = 0; k0 < K; k0 += 32) {
    __syncthreads();
    gload16(ag + k0, asd);
    gload16(ag + (size_t)64 * K + k0, asd + 2048 * 8 / 8 * 0 + 2048);
    gload16(bg + k0, bsd);
    gload16(bg + (size_t)64 * K + k0, bsd + 2048);
    __syncthreads();
    bf16x8 af[4], bfr[4];
    #pragma unroll
    for (int m = 0; m < 4; ++m)
      af[m] = *(const bf16x8*)(As + (arow + m * 16) * 32 + fk);
    #pragma unroll
    for (int n = 0; n < 4; ++n)
      bfr[n] = *(const bf16x8*)(Bs + (brow + n * 16) * 32 + fk);
    #pragma unroll
    for (int m = 0; m < 4; ++m)
      #pragma unroll
      for (int n = 0; n < 4; ++n)
        acc[m][n] = __builtin_amdgcn_mfma_f32_16x16x32_bf16(af[m], bfr[n], acc[m][n], 0, 0, 0);
  }
}

// ---------------------------------------------------------------------------
// QKV GEMM: Xbf[3200][768] * Wbf[2304][768]^T -> scatter f32 q/k/v [B,NH,L,HD]
// ---------------------------------------------------------------------------
__global__ __launch_bounds__(256) void qkv_gemm_mfma(
    const unsigned short* __restrict__ Xbf, const unsigned short* __restrict__ Wbf,
    float* __restrict__ q_raw, float* __restrict__ k_raw, float* __restrict__ v_raw) {
  f32x4 acc[4][4] = {};
  const int m0 = blockIdx.y * 128;
  const int n0 = blockIdx.x * 128;
  gemm_core(Xbf, Wbf, C_, m0, n0, acc);
  const int lane = threadIdx.x & 63;
  const int wv = threadIdx.x >> 6;
  const int wm = wv >> 1, wn = wv & 1;
  const int fr = lane & 15, fj = (lane >> 4) * 4;
  #pragma unroll
  for (int n = 0; n < 4; ++n) {
    const int gn = n0 + wn * 64 + n * 16 + fr;
    const int which = (gn >= 2 * C_) ? 2 : ((gn >= C_) ? 1 : 0);
    const int rem = gn - which * C_;
    const int h = rem >> 6, d = rem & 63;
    float* dst = (which == 0) ? q_raw : ((which == 1) ? k_raw : v_raw);
    #pragma unroll
    for (int m = 0; m < 4; ++m) {
      #pragma unroll
      for (int j = 0; j < 4; ++j) {
        const int gm = m0 + wm * 64 + m * 16 + fj + j;
        if (gm < B_ * L_) {
          const int b = (gm >= L_) ? 1 : 0;
          const int l = gm - b * L_;
          dst[(((size_t)b * NH_ + h) * L_ + l) * HD_ + d] = acc[m][n][j];
        }
      }
    }
  }
}

// ---------------------------------------------------------------------------
// Proj GEMM: Abf[3200][768] * Wobf[768][768]^T + bo -> d_out f32 [3136][768]
// ---------------------------------------------------------------------------
__global__ __launch_bounds__(256) void proj_gemm_mfma(
    const unsigned short* __restrict__ Abf, const unsigned short* __restrict__ Wobf,
    const float* __restrict__ bo, float* __restrict__ out) {
  f32x4 acc[4][4] = {};
  const int m0 = blockIdx.y * 128;
  const int n0 = blockIdx.x * 128;
  gemm_core(Abf, Wobf, C_, m0, n0, acc);
  const int lane = threadIdx.x & 63;
  const int wv = threadIdx.x >> 6;
  const int wm = wv >> 1, wn = wv & 1;
  const int fr = lane & 15, fj = (lane >> 4) * 4;
  #pragma unroll
  for (int n = 0; n < 4; ++n) {
    const int gn = n0 + wn * 64 + n * 16 + fr;
    const float bias = bo[gn];
    #pragma unroll
    for (int m = 0; m < 4; ++m) {
      #pragma unroll
      for (int j = 0; j < 4; ++j) {
        const int gm = m0 + wm * 64 + m * 16 + fj + j;
        if (gm < B_ * L_) out[(size_t)gm * C_ + gn] = acc[m][n][j] + bias;
      }
    }
  }
}

// ---------------------------------------------------------------------------
// Depthwise 3x3 conv + LayerNorm(64). bf16 out (scaled), stride-able.
// ---------------------------------------------------------------------------
__global__ __launch_bounds__(256) void pool_ln_multi(
    const float* __restrict__ in, const float* __restrict__ w,
    const float* __restrict__ g, const float* __restrict__ bta,
    unsigned short* __restrict__ bf16out, int bfstride, float scale) {
  const int row = blockIdx.x * 4 + (threadIdx.x >> 6);
  const int d = threadIdx.x & 63;
  const int bh = row / L_;
  const int l  = row % L_;
  const int t  = l / S_;
  const int sq = l % S_;
  const int x = sq / W_, y = sq % W_;
  const float* base = in + ((size_t)bh * L_ + t * S_) * HD_;
  float acc = 0.f;
  #pragma unroll
  for (int dx = 0; dx < 3; ++dx) {
    const int xx = x + dx - 1;
    if (xx < 0 || xx >= H_) continue;
    #pragma unroll
    for (int dy = 0; dy < 3; ++dy) {
      const int yy = y + dy - 1;
      if (yy < 0 || yy >= W_) continue;
      acc += base[(size_t)(xx * W_ + yy) * HD_ + d] * w[(dx * 3 + dy) * HD_ + d];
    }
  }
  float s = acc;
  #pragma unroll
  for (int off = 32; off; off >>= 1) s += __shfl_xor(s, off);
  const float mu = s * (1.f / 64.f);
  const float dv = acc - mu;
  float s2 = dv * dv;
  #pragma unroll
  for (int off = 32; off; off >>= 1) s2 += __shfl_xor(s2, off);
  const float var = s2 * (1.f / 64.f);
  const float val = dv * rsqrtf(var + LN_EPS) * g[d] + bta[d];
  bf16out[(size_t)row * bfstride + d] = f2bf(val * scale);
}

// ---------------------------------------------------------------------------
// Transpose V per head: Vtmp [bh][L][64] bf16 -> VpT [bh][64][L] bf16
// ---------------------------------------------------------------------------
__global__ __launch_bounds__(256) void transpose_v(
    const unsigned short* __restrict__ Vtmp, unsigned short* __restrict__ VpT) {
  __shared__ unsigned short tile[32][72];
  const int bh = blockIdx.y;
  const int l0 = blockIdx.x * 32;
  const int t = threadIdx.x;
  {
    const int r = t >> 3, c8 = (t & 7) * 8;
    u32x4 v = *(const u32x4*)(Vtmp + ((size_t)bh * L_ + l0 + r) * 64 + c8);
    *(u32x4*)&tile[r][c8] = v;
  }
  __syncthreads();
  const int d = t >> 2, gq = t & 3;
  unsigned short o[8];
  #pragma unroll
  for (int i = 0; i < 8; ++i) o[i] = tile[gq*8 + i][d];
  u32x4 ov;
  ov.x = (uint_)o[0] | ((uint_)o[1] << 16);
  ov.y = (uint_)o[2] | ((uint_)o[3] << 16);
  ov.z = (uint_)o[4] | ((uint_)o[5] << 16);
  ov.w = (uint_)o[6] | ((uint_)o[7] << 16);
  *(u32x4*)(VpT + ((size_t)bh * 64 + d) * L_ + l0 + gq*8) = ov;
}

// ---------------------------------------------------------------------------
// rel-pos rows -> Qp2 dims 64..175 (log2e-scaled bf16; other T-block zeroed)
// reads bf16 q from Qp2 dims 0..63
// ---------------------------------------------------------------------------
__global__ void relpos_fused(
    const unsigned short* __restrict__ Qp2r, const float* __restrict__ rph,
    const float* __restrict__ rpw, unsigned short* __restrict__ Qp2) {
  const int idx = blockIdx.x * blockDim.x + threadIdx.x;
  const int k = idx % H_;
  const int rest = idx / H_;            // bh*L + t*S + sq
  const int sq = rest % S_;
  const int t = (rest % L_) / S_;
  const int x = sq / W_, y = sq % W_;
  const unsigned short* qrow = Qp2r + (size_t)rest * DP_;
  const float* rh = rph + (x - k + H_ - 1) * HD_;
  const float* rw = rpw + (y - k + W_ - 1) * HD_;
  float ah = 0.f, aw = 0.f;
  #pragma unroll 8
  for (int c = 0; c < HD_; ++c) {
    const float qv = bf2f(qrow[c]);
    ah += qv * rh[c];
    aw += qv * rw[c];
  }
  unsigned short* qd = Qp2 + (size_t)rest * DP_;
  qd[64 + t*56 + k]        = f2bf(ah * LOG2E);
  qd[64 + t*56 + 28 + k]   = f2bf(aw * LOG2E);
  qd[64 + (1-t)*56 + k]      = 0;
  qd[64 + (1-t)*56 + 28 + k] = 0;
}

// ---------------------------------------------------------------------------
// MFMA flash attention. Block = 128 thr (2 waves), grid (49, 24).
// Writes residual-added bf16 output in [B][L][C] layout (A of proj GEMM).
// ---------------------------------------------------------------------------
__device__ __forceinline__ void load_tile(
    const unsigned short* kbase, const unsigned short* vbase0, int kt,
    u32x4& k0, u32x4& k1, u32x4& k2, u32x4& k3,
    u32x4& va, u32x4& vb, u32x4& vc, u32x4& vd) {
  const unsigned short* kr = kbase + (size_t)kt * 2048;
  k0 = *(const u32x4*)(kr);
  k1 = *(const u32x4*)(kr + 16);
  k2 = *(const u32x4*)(kr + 32);
  k3 = *(const u32x4*)(kr + 48);
  const unsigned short* vr = vbase0 + kt * 32;
  va = *(const u32x4*)(vr);
  vb = *(const u32x4*)(vr + 16);
  vc = *(const u32x4*)(vr + 32 * L_);
  vd = *(const u32x4*)(vr + 32 * L_ + 16);
}

__device__ __forceinline__ void proc_tile(
    int kt, int lo, int hi, const u32x4 (&qf)[11],
    u32x4 k0, u32x4 k1, u32x4 k2, u32x4 k3,
    u32x4 va, u32x4 vb, u32x4 vc, u32x4 vd,
    f32x16& acc0, f32x16& acc1, float& m_run, float& l_run) {
  const int kr = kt * 32 + lo;
  const int t = (kr >= S_) ? 1 : 0;
  const int sk = kr - t * S_;
  const int x = sk / W_, y = sk - x * W_;
  const int p1 = 64 + t*56 + x;
  const int p2 = 64 + t*56 + 28 + y;
  const uint_ v1 = 0x3F80u << ((p1 & 1) << 4);
  const uint_ v2 = 0x3F80u << ((p2 & 1) << 4);
  const int g1 = p1 >> 3, g2 = p2 >> 3;
  const int w1 = (p1 >> 1) & 3, w2 = (p2 >> 1) & 3;

  f32x16 s = {};
  s = __builtin_amdgcn_mfma_f32_32x32x16_bf16(BC8(k0), BC8(qf[0]), s, 0, 0, 0);
  s = __builtin_amdgcn_mfma_f32_32x32x16_bf16(BC8(k1), BC8(qf[1]), s, 0, 0, 0);
  s = __builtin_amdgcn_mfma_f32_32x32x16_bf16(BC8(k2), BC8(qf[2]), s, 0, 0, 0);
  s = __builtin_amdgcn_mfma_f32_32x32x16_bf16(BC8(k3), BC8(qf[3]), s, 0, 0, 0);
  #pragma unroll
  for (int c = 4; c < 11; ++c) {
    const int gg = 2*c + hi;
    u32x4 oh;
    oh.x = ((g1 == gg && w1 == 0) ? v1 : 0u) | ((g2 == gg && w2 == 0) ? v2 : 0u);
    oh.y = ((g1 == gg && w1 == 1) ? v1 : 0u) | ((g2 == gg && w2 == 1) ? v2 : 0u);
    oh.z = ((g1 == gg && w1 == 2) ? v1 : 0u) | ((g2 == gg && w2 == 2) ? v2 : 0u);
    oh.w = ((g1 == gg && w1 == 3) ? v1 : 0u) | ((g2 == gg && w2 == 3) ? v2 : 0u);
    s = __builtin_amdgcn_mfma_f32_32x32x16_bf16(BC8(oh), BC8(qf[c]), s, 0, 0, 0);
  }

  float pmax = s[0];
  #pragma unroll
  for (int r = 1; r < 16; ++r) pmax = fmaxf(pmax, s[r]);
  pmax = fmaxf(pmax, __shfl_xor(pmax, 32));
  if (__any(pmax > m_run + 8.f)) {
    const float mn = fmaxf(m_run, pmax);
    const float f = exp2f(m_run - mn);
    m_run = mn; l_run *= f;
    #pragma unroll
    for (int r = 0; r < 16; ++r) {
      const float fr = __shfl(f, (r & 3) + 8*(r >> 2) + 4*hi);
      acc0[r] *= fr; acc1[r] *= fr;
    }
  }
  float ps = 0.f;
  uint_ pw0, pw1, pw2, pw3, pw4, pw5, pw6, pw7;
  {
    float a, b;
    a = exp2f(s[0]-m_run);  b = exp2f(s[1]-m_run);  ps += a+b; pw0 = cvtpk(a,b);
    a = exp2f(s[2]-m_run);  b = exp2f(s[3]-m_run);  ps += a+b; pw1 = cvtpk(a,b);
    a = exp2f(s[4]-m_run);  b = exp2f(s[5]-m_run);  ps += a+b; pw2 = cvtpk(a,b);
    a = exp2f(s[6]-m_run);  b = exp2f(s[7]-m_run);  ps += a+b; pw3 = cvtpk(a,b);
    a = exp2f(s[8]-m_run);  b = exp2f(s[9]-m_run);  ps += a+b; pw4 = cvtpk(a,b);
    a = exp2f(s[10]-m_run); b = exp2f(s[11]-m_run); ps += a+b; pw5 = cvtpk(a,b);
    a = exp2f(s[12]-m_run); b = exp2f(s[13]-m_run); ps += a+b; pw6 = cvtpk(a,b);
    a = exp2f(s[14]-m_run); b = exp2f(s[15]-m_run); ps += a+b; pw7 = cvtpk(a,b);
  }
  ps += __shfl_xor(ps, 32);
  l_run += ps;

  auto sA = __builtin_amdgcn_permlane32_swap(pw0, pw2, false, false);
  auto sB = __builtin_amdgcn_permlane32_swap(pw1, pw3, false, false);
  auto sC = __builtin_amdgcn_permlane32_swap(pw4, pw6, false, false);
  auto sD = __builtin_amdgcn_permlane32_swap(pw5, pw7, false, false);
  u32x4 pa0, pa1;
  pa0.x = sA[0]; pa0.y = sB[0]; pa0.z = sA[1]; pa0.w = sB[1];
  pa1.x = sC[0]; pa1.y = sD[0]; pa1.z = sC[1]; pa1.w = sD[1];

  acc0 = __builtin_amdgcn_mfma_f32_32x32x16_bf16(BC8(pa0), BC8(va), acc0, 0, 0, 0);
  acc0 = __builtin_amdgcn_mfma_f32_32x32x16_bf16(BC8(pa1), BC8(vb), acc0, 0, 0, 0);
  acc1 = __builtin_amdgcn_mfma_f32_32x32x16_bf16(BC8(pa0), BC8(vc), acc1, 0, 0, 0);
  acc1 = __builtin_amdgcn_mfma_f32_32x32x16_bf16(BC8(pa1), BC8(vd), acc1, 0, 0, 0);
}

__global__ __launch_bounds__(128) void attn_mfma(
    const unsigned short* __restrict__ Qp2, const unsigned short* __restrict__ Kp2a,
    const unsigned short* __restrict__ VpT, unsigned short* __restrict__ Abf) {
  __shared__ float red_acc[32][64];
  __shared__ float red_ml[2][2][32];

  const int lane = threadIdx.x & 63;
  const int wv = threadIdx.x >> 6;
  const int lo = lane & 31, hi = lane >> 5;
  const int qt = blockIdx.x;
  const int bh = blockIdx.y;
  const int q0 = qt * 32;

  u32x4 qf[11];
  {
    const unsigned short* qrow = Qp2 + ((size_t)bh * L_ + q0 + lo) * DP_ + hi * 8;
    #pragma unroll
    for (int c = 0; c < 11; ++c) qf[c] = *(const u32x4*)(qrow + c * 16);
  }

  const unsigned short* kbase = Kp2a + ((size_t)bh * L_ + lo) * 64 + hi * 8;
  const unsigned short* vbase0 = VpT + (size_t)bh * 64 * L_ + (size_t)lo * L_ + hi * 8;

  f32x16 acc0 = {}, acc1 = {};
  float m_run = -1e30f, l_run = 0.f;
  const int nt = 25 - wv;
  const int tb = wv * 25;

  u32x4 ck0, ck1, ck2, ck3, cva, cvb, cvc, cvd;
  u32x4 nk0, nk1, nk2, nk3, nva, nvb, nvc, nvd;
  load_tile(kbase, vbase0, tb, ck0, ck1, ck2, ck3, cva, cvb, cvc, cvd);
  int i = 0;
  for (; i + 2 <= nt; i += 2) {
    load_tile(kbase, vbase0, tb + i + 1, nk0, nk1, nk2, nk3, nva, nvb, nvc, nvd);
    proc_tile(tb + i, lo, hi, qf, ck0, ck1, ck2, ck3, cva, cvb, cvc, cvd,
              acc0, acc1, m_run, l_run);
    const int nxt = tb + ((i + 2 < nt) ? i + 2 : nt - 1);
    load_tile(kbase, vbase0, nxt, ck0, ck1, ck2, ck3, cva, cvb, cvc, cvd);
    proc_tile(tb + i + 1, lo, hi, qf, nk0, nk1, nk2, nk3, nva, nvb, nvc, nvd,
              acc0, acc1, m_run, l_run);
  }
  if (i < nt)
    proc_tile(tb + i, lo, hi, qf, ck0, ck1, ck2, ck3, cva, cvb, cvc, cvd,
              acc0, acc1, m_run, l_run);

  if (hi == 0) { red_ml[wv][0][lo] = m_run; red_ml[wv][1][lo] = l_run; }
  if (wv == 1) {
    #pragma unroll
    for (int r = 0; r < 16; ++r) {
      const int row = (r & 3) + 8*(r >> 2) + 4*hi;
      red_acc[row][lo]      = acc0[r];
      red_acc[row][32 + lo] = acc1[r];
    }
  }
  __syncthreads();
  if (wv == 0) {
    const int b = bh / NH_, h = bh % NH_;
    #pragma unroll
    for (int r = 0; r < 16; ++r) {
      const int row = (r & 3) + 8*(r >> 2) + 4*hi;
      const float m0 = red_ml[0][0][row], l0 = red_ml[0][1][row];
      const float m1 = red_ml[1][0][row], l1 = red_ml[1][1][row];
      const float M = fmaxf(m0, m1);
      const float w0 = exp2f(m0 - M), w1 = exp2f(m1 - M);
      const float inv = 1.0f / (l0 * w0 + l1 * w1);
      const size_t qoff = ((size_t)bh * L_ + q0 + row) * DP_ + lo;
      const float o0 = (acc0[r] * w0 + red_acc[row][lo] * w1) * inv + bf2f(Qp2[qoff]);
      const float o1 = (acc1[r] * w0 + red_acc[row][32 + lo] * w1) * inv + bf2f(Qp2[qoff + 32]);
      const size_t ooff = ((size_t)(b * L_ + q0 + row)) * C_ + h * 64 + lo;
      Abf[ooff]      = f2bf(o0);
      Abf[ooff + 32] = f2bf(o1);
    }
  }
}

// ---------------------------------------------------------------------------
extern "C" void kernel_launch(void* const* d_in, const int* in_sizes, int n_in,
                              void* d_out, int out_size, void* d_ws, size_t ws_size,
                              hipStream_t stream) {
  const float* x         = (const float*)d_in[0];
  const float* qkv_w     = (const float*)d_in[1];
  const float* out_w     = (const float*)d_in[2];
  const float* out_b     = (const float*)d_in[3];
  const float* q_pool_w  = (const float*)d_in[4];
  const float* k_pool_w  = (const float*)d_in[5];
  const float* v_pool_w  = (const float*)d_in[6];
  const float* q_ln_g    = (const float*)d_in[7];
  const float* q_ln_b    = (const float*)d_in[8];
  const float* k_ln_g    = (const float*)d_in[9];
  const float* k_ln_b    = (const float*)d_in[10];
  const float* v_ln_g    = (const float*)d_in[11];
  const float* v_ln_b    = (const float*)d_in[12];
  const float* rel_pos_h = (const float*)d_in[13];
  const float* rel_pos_w = (const float*)d_in[14];

  float* R = (float*)d_ws;
  const size_t NQ = (size_t)B_ * NH_ * L_ * HD_;   // 2,408,448
  // layout (f32 slots):
  float* q_raw = R;                                   // [0, NQ)
  unsigned short* Abf = (unsigned short*)R;           // alias, after pool_q; 3200*768 bf16
  float* k_raw = R + NQ;                              // [NQ, 2NQ)
  unsigned short* Qp2 = (unsigned short*)(R + NQ);    // 24*1568*176 bf16 = 1.375NQ slots
  float* v_raw = R + 2*NQ;                            // [2NQ, 3NQ)
  unsigned short* Vtmp = (unsigned short*)(R + 3*NQ); // NQ bf16 -> 0.5NQ slots
  unsigned short* Kp2a = (unsigned short*)(R + 3*NQ + NQ/2);
  unsigned short* Xbf  = (unsigned short*)(R + 4*NQ); // 3200*768 bf16 = 1,228,800 slots
  unsigned short* VpT  = (unsigned short*)(R + 4*NQ); // alias Xbf (after qkv_gemm)
  unsigned short* Wbf  = (unsigned short*)(R + 4*NQ + 1228800);  // 2304*768 bf16
  unsigned short* Wobf = (unsigned short*)(R + 4*NQ + 1228800 + 884736); // 768*768 bf16

  cvt_bf16<<<1200, 256, 0, stream>>>(x, Xbf, 3136*768, 3200*768);
  cvt_bf16<<<864, 256, 0, stream>>>(qkv_w, Wbf, 2304*768, 2304*768);
  cvt_bf16<<<288, 256, 0, stream>>>(out_w, Wobf, 768*768, 768*768);
  qkv_gemm_mfma<<<dim3(18, 25), 256, 0, stream>>>(Xbf, Wbf, q_raw, k_raw, v_raw);
  pool_ln_multi<<<9408, 256, 0, stream>>>(k_raw, k_pool_w, k_ln_g, k_ln_b, Kp2a, 64, SCALE_K);
  pool_ln_multi<<<9408, 256, 0, stream>>>(v_raw, v_pool_w, v_ln_g, v_ln_b, Vtmp, 64, 1.f);
  pool_ln_multi<<<9408, 256, 0, stream>>>(q_raw, q_pool_w, q_ln_g, q_ln_b, Qp2, DP_, 1.f);
  cvt_bf16<<<24, 256, 0, stream>>>(nullptr, Abf + 3136*768, 0, 64*768);  // zero pad rows
  transpose_v<<<dim3(49, 24), 256, 0, stream>>>(Vtmp, VpT);
  relpos_fused<<<4116, 256, 0, stream>>>(Qp2, rel_pos_h, rel_pos_w, Qp2);
  attn_mfma<<<dim3(49, 24), 128, 0, stream>>>(Qp2, Kp2a, VpT, Abf);
  proj_gemm_mfma<<<dim3(6, 25), 256, 0, stream>>>(Abf, Wobf, out_b, (float*)d_out);
}